// Round 2
// baseline (479.853 us; speedup 1.0000x reference)
//
#include <hip/hip_runtime.h>

#define B 32
#define D 1024
#define UD 256
#define ENT 32
#define NENT 64
#define S 2048
#define C 65

__device__ __forceinline__ float dot4(float4 w, const float* q) {
    return w.x * q[0] + w.y * q[1] + w.z * q[2] + w.w * q[3];
}

__global__ __launch_bounds__(256) void k_zero(float* __restrict__ p) {
    p[blockIdx.x * 256 + threadIdx.x] = 0.f;
}

// grid (20, 8): x = 64-row group of [W_unit; W_chunk] (1280 rows), y = 4-batch group.
// thread = (jl 0..63, kq 0..3); 4 batch-accumulators per thread over a 256-k quarter.
__global__ __launch_bounds__(256) void k_proj(const float* __restrict__ src,
                                              const float* __restrict__ Wu,
                                              const float* __restrict__ Wc,
                                              float* __restrict__ qu,
                                              float* __restrict__ qc) {
    __shared__ alignas(16) float s_src[4][D];       // 16 KB
    __shared__ float red[4][64][4];                 // 4 KB
    int t = threadIdx.x, rg = blockIdx.x, bg = blockIdx.y;
    // stage 4 batches of source
    for (int f = t; f < 4 * (D / 4); f += 256) {
        int bb = f >> 8, i4 = f & 255;
        float4 v = *(const float4*)(src + (size_t)(bg * 4 + bb) * D + i4 * 4);
        *(float4*)(&s_src[bb][i4 * 4]) = v;
    }
    __syncthreads();
    int jl = t & 63, kq = t >> 6;
    int gj = rg * 64 + jl;
    const float* wrow = (gj < UD) ? (Wu + (size_t)gj * D) : (Wc + (size_t)(gj - UD) * D);
    const float4* wp = (const float4*)wrow + kq * 64;   // 64 float4 = 256 k
    float acc[4] = {0.f, 0.f, 0.f, 0.f};
#pragma unroll 4
    for (int i = 0; i < 64; ++i) {
        float4 w = wp[i];
        int k = kq * 256 + i * 4;
#pragma unroll
        for (int bb = 0; bb < 4; ++bb) acc[bb] += dot4(w, &s_src[bb][k]);
    }
#pragma unroll
    for (int bb = 0; bb < 4; ++bb) red[kq][jl][bb] = acc[bb];
    __syncthreads();
    {
        int jl2 = t & 63, bb = t >> 6;
        float s = red[0][jl2][bb] + red[1][jl2][bb] + red[2][jl2][bb] + red[3][jl2][bb];
        int gj2 = rg * 64 + jl2, b = bg * 4 + bb;
        if (gj2 < UD) qu[b * UD + gj2] = s;
        else qc[b * D + (gj2 - UD)] = s;
    }
}

// grid (NENT, B): per-entity unit scores + masked softmax over ENT=32
__global__ __launch_bounds__(256) void k_units(const float* __restrict__ pe,
                                               const int* __restrict__ lmask,
                                               const float* __restrict__ qu,
                                               float* __restrict__ out_au) {
    __shared__ alignas(16) float q[UD];
    __shared__ float part[256];
    int n = blockIdx.x, b = blockIdx.y, t = threadIdx.x;
    q[t] = qu[b * UD + t];
    __syncthreads();
    int e = t >> 3, r = t & 7;  // entity, k-eighth
    const float4* pp = (const float4*)(pe + (size_t)(n * ENT + e) * B * UD + (size_t)b * UD) + r * 8;
    float acc = 0.f;
#pragma unroll
    for (int i = 0; i < 8; ++i) acc += dot4(pp[i], &q[(r * 8 + i) * 4]);
    part[t] = acc;
    __syncthreads();
    if (t < ENT) {
        float sc = 0.f;
#pragma unroll
        for (int r2 = 0; r2 < 8; ++r2) sc += part[t * 8 + r2];
        bool m = lmask[(size_t)n * B * ENT + b * ENT + t] != 0;
        float v = m ? -1e30f : sc;
        float mx = v;
        for (int o = 16; o >= 1; o >>= 1) mx = fmaxf(mx, __shfl_xor(mx, o));
        float p = m ? 0.f : __expf(v - mx);
        float sm = p;
        for (int o = 16; o >= 1; o >>= 1) sm += __shfl_xor(sm, o);
        out_au[b * S + n * ENT + t] = (sm > 0.f) ? (p / sm) : 0.f;
    }
}

// grid (C, B), 64 threads: one chunk score per block
__global__ __launch_bounds__(64) void k_cscore(const float* __restrict__ hl,
                                               const float* __restrict__ qc,
                                               float* __restrict__ scores) {
    int c = blockIdx.x, b = blockIdx.y, l = threadIdx.x;
    const float4* hp = (const float4*)(hl + (size_t)(c * B + b) * D);
    const float4* qp = (const float4*)(qc + (size_t)b * D);
    float acc = 0.f;
#pragma unroll
    for (int i = 0; i < 4; ++i) {
        int f = l + 64 * i;
        float4 h = hp[f], q = qp[f];
        acc += h.x * q.x + h.y * q.y + h.z * q.z + h.w * q.w;
    }
    for (int o = 32; o >= 1; o >>= 1) acc += __shfl_xor(acc, o);
    if (l == 0) scores[b * C + c] = acc;
}

// grid (B), 128 threads: masked softmax over 65 chunks, drop chunk 0
__global__ __launch_bounds__(128) void k_csoft(const float* __restrict__ scores,
                                               const int* __restrict__ hmask,
                                               float* __restrict__ out_ac) {
    __shared__ float sc[C];
    __shared__ float red[2];
    int b = blockIdx.x, t = threadIdx.x;
    if (t < C) sc[t] = scores[b * C + t];
    __syncthreads();
    if (t == 0) {
        float mx = -1e30f;
        for (int c = 0; c < C; ++c) {
            float v = hmask[b * C + c] ? -1e30f : sc[c];
            mx = fmaxf(mx, v);
        }
        float sm = 0.f;
        for (int c = 0; c < C; ++c) {
            float v = hmask[b * C + c] ? -1e30f : sc[c];
            sm += __expf(v - mx);
        }
        red[0] = mx;
        red[1] = sm;
    }
    __syncthreads();
    if (t >= 1 && t < C) {
        bool m = hmask[b * C + t] != 0;
        float p = m ? 0.f : __expf(sc[t] - red[0]) / red[1];
        out_ac[b * NENT + (t - 1)] = p;
    }
}

// grid (NENT, B): av = ac[n]*au, write av; c += sum_e av[e]*ll[row e] (fp32 atomics)
__global__ __launch_bounds__(256) void k_ctx(const float* __restrict__ ll,
                                             const float* __restrict__ out_au,
                                             const float* __restrict__ out_ac,
                                             float* __restrict__ cf,
                                             float* __restrict__ out_av) {
    __shared__ float av[ENT];
    int n = blockIdx.x, b = blockIdx.y, t = threadIdx.x;
    if (t < ENT) {
        float a = out_ac[b * NENT + n] * out_au[b * S + n * ENT + t];
        av[t] = a;
        out_av[b * S + n * ENT + t] = a;
    }
    __syncthreads();
    float a0 = 0.f, a1 = 0.f, a2 = 0.f, a3 = 0.f;
    const float* base = ll + (size_t)(n * ENT) * B * D + (size_t)b * D + t * 4;
#pragma unroll 4
    for (int e = 0; e < ENT; ++e) {
        float4 x = *(const float4*)(base + (size_t)e * B * D);
        float wv = av[e];
        a0 += wv * x.x;
        a1 += wv * x.y;
        a2 += wv * x.z;
        a3 += wv * x.w;
    }
    float* cp = cf + b * D + t * 4;
    atomicAdd(cp + 0, a0);
    atomicAdd(cp + 1, a1);
    atomicAdd(cp + 2, a2);
    atomicAdd(cp + 3, a3);
}

// grid (16, 8): x = 64-row group of W_out, y = 4-batch group.
// Linear block id = x + 16*y -> all 8 blocks sharing a Wo slice land on one XCD (L2 reuse).
__global__ __launch_bounds__(256) void k_out(const float* __restrict__ Wo,
                                             const float* __restrict__ src,
                                             const float* __restrict__ cf,
                                             float* __restrict__ out_h) {
    __shared__ alignas(16) float cc[4][2 * D];      // 32 KB concat for 4 batches
    __shared__ float red[4][64][4];                 // 4 KB
    int t = threadIdx.x, jg = blockIdx.x, bg = blockIdx.y;
    for (int f = t; f < 4 * (2 * D / 4); f += 256) {  // 2048 float4s
        int bb = f >> 9, part = f & 511;
        int b = bg * 4 + bb;
        float4 v;
        if (part < 256) v = *(const float4*)(cf + (size_t)b * D + part * 4);
        else v = *(const float4*)(src + (size_t)b * D + (part - 256) * 4);
        *(float4*)(&cc[bb][part * 4]) = v;
    }
    __syncthreads();
    int jl = t & 63, kq = t >> 6;
    int j = jg * 64 + jl;
    const float4* wp = (const float4*)(Wo + (size_t)j * 2 * D) + kq * 128;  // 512 k
    float acc[4] = {0.f, 0.f, 0.f, 0.f};
#pragma unroll 4
    for (int i = 0; i < 128; ++i) {
        float4 w = wp[i];
        int k = kq * 512 + i * 4;
#pragma unroll
        for (int bb = 0; bb < 4; ++bb) acc[bb] += dot4(w, &cc[bb][k]);
    }
#pragma unroll
    for (int bb = 0; bb < 4; ++bb) red[kq][jl][bb] = acc[bb];
    __syncthreads();
    {
        int jl2 = t & 63, bb = t >> 6;
        float s = red[0][jl2][bb] + red[1][jl2][bb] + red[2][jl2][bb] + red[3][jl2][bb];
        out_h[(size_t)(bg * 4 + bb) * D + jg * 64 + jl2] = tanhf(s);
    }
}

extern "C" void kernel_launch(void* const* d_in, const int* in_sizes, int n_in,
                              void* d_out, int out_size, void* d_ws, size_t ws_size,
                              hipStream_t stream) {
    const float* src = (const float*)d_in[0];
    const float* hl = (const float*)d_in[1];
    const float* pe = (const float*)d_in[2];
    const float* ll = (const float*)d_in[3];
    const int* lmask = (const int*)d_in[4];
    const int* hmask = (const int*)d_in[5];
    const float* Wu = (const float*)d_in[6];
    const float* Wc = (const float*)d_in[7];
    const float* Wo = (const float*)d_in[8];

    float* out = (float*)d_out;
    float* out_h = out;                      // (B, D)
    float* out_av = out + B * D;             // (B, S)
    float* out_ac = out_av + B * S;          // (B, NENT)
    float* out_au = out_ac + B * NENT;       // (B, S)

    float* ws = (float*)d_ws;
    float* qu = ws;                          // B*UD
    float* qc = qu + B * UD;                 // B*D
    float* cf = qc + B * D;                  // B*D
    float* scores = cf + B * D;              // B*C

    k_zero<<<dim3(B * D / 256), 256, 0, stream>>>(cf);
    k_proj<<<dim3(20, 8), 256, 0, stream>>>(src, Wu, Wc, qu, qc);
    k_units<<<dim3(NENT, B), 256, 0, stream>>>(pe, lmask, qu, out_au);
    k_cscore<<<dim3(C, B), 64, 0, stream>>>(hl, qc, scores);
    k_csoft<<<dim3(B), 128, 0, stream>>>(scores, hmask, out_ac);
    k_ctx<<<dim3(NENT, B), 256, 0, stream>>>(ll, out_au, out_ac, cf, out_av);
    k_out<<<dim3(16, 8), 256, 0, stream>>>(Wo, src, cf, out_h);
}

// Round 3
// 477.981 us; speedup vs baseline: 1.0039x; 1.0039x over previous
//
#include <hip/hip_runtime.h>

#define B 32
#define D 1024
#define UD 256
#define ENT 32
#define NENT 64
#define S 2048
#define C 65

__device__ __forceinline__ float dot4(float4 w, const float* q) {
    return w.x * q[0] + w.y * q[1] + w.z * q[2] + w.w * q[3];
}

// grid (20, 8): x = 64-row group of [W_unit; W_chunk] (1280 rows), y = 4-batch group.
__global__ __launch_bounds__(256) void k_proj(const float* __restrict__ src,
                                              const float* __restrict__ Wu,
                                              const float* __restrict__ Wc,
                                              float* __restrict__ qu,
                                              float* __restrict__ qc) {
    __shared__ alignas(16) float s_src[4][D];       // 16 KB
    __shared__ float red[4][64][4];                 // 4 KB
    int t = threadIdx.x, rg = blockIdx.x, bg = blockIdx.y;
    for (int f = t; f < 4 * (D / 4); f += 256) {
        int bb = f >> 8, i4 = f & 255;
        float4 v = *(const float4*)(src + (size_t)(bg * 4 + bb) * D + i4 * 4);
        *(float4*)(&s_src[bb][i4 * 4]) = v;
    }
    __syncthreads();
    int jl = t & 63, kq = t >> 6;
    int gj = rg * 64 + jl;
    const float* wrow = (gj < UD) ? (Wu + (size_t)gj * D) : (Wc + (size_t)(gj - UD) * D);
    const float4* wp = (const float4*)wrow + kq * 64;   // 64 float4 = 256 k
    float acc[4] = {0.f, 0.f, 0.f, 0.f};
#pragma unroll 4
    for (int i = 0; i < 64; ++i) {
        float4 w = wp[i];
        int k = kq * 256 + i * 4;
#pragma unroll
        for (int bb = 0; bb < 4; ++bb) acc[bb] += dot4(w, &s_src[bb][k]);
    }
#pragma unroll
    for (int bb = 0; bb < 4; ++bb) red[kq][jl][bb] = acc[bb];
    __syncthreads();
    {
        int jl2 = t & 63, bb = t >> 6;
        float s = red[0][jl2][bb] + red[1][jl2][bb] + red[2][jl2][bb] + red[3][jl2][bb];
        int gj2 = rg * 64 + jl2, b = bg * 4 + bb;
        if (gj2 < UD) qu[b * UD + gj2] = s;
        else qc[b * D + (gj2 - UD)] = s;
    }
}

// grid (NENT, B): per-entity unit scores + masked softmax over ENT=32
__global__ __launch_bounds__(256) void k_units(const float* __restrict__ pe,
                                               const int* __restrict__ lmask,
                                               const float* __restrict__ qu,
                                               float* __restrict__ out_au) {
    __shared__ alignas(16) float q[UD];
    __shared__ float part[256];
    int n = blockIdx.x, b = blockIdx.y, t = threadIdx.x;
    q[t] = qu[b * UD + t];
    __syncthreads();
    int e = t >> 3, r = t & 7;  // entity, k-eighth (lanes 0..7 contiguous in k -> coalesced)
    const float4* pp = (const float4*)(pe + (size_t)(n * ENT + e) * B * UD + (size_t)b * UD) + r * 8;
    float acc = 0.f;
#pragma unroll
    for (int i = 0; i < 8; ++i) acc += dot4(pp[i], &q[(r * 8 + i) * 4]);
    part[t] = acc;
    __syncthreads();
    if (t < ENT) {
        float sc = 0.f;
#pragma unroll
        for (int r2 = 0; r2 < 8; ++r2) sc += part[t * 8 + r2];
        bool m = lmask[(size_t)n * B * ENT + b * ENT + t] != 0;
        float v = m ? -1e30f : sc;
        float mx = v;
        for (int o = 16; o >= 1; o >>= 1) mx = fmaxf(mx, __shfl_xor(mx, o));
        float p = m ? 0.f : __expf(v - mx);
        float sm = p;
        for (int o = 16; o >= 1; o >>= 1) sm += __shfl_xor(sm, o);
        out_au[b * S + n * ENT + t] = (sm > 0.f) ? (p / sm) : 0.f;
    }
}

// grid (B), 256 threads: chunk scores (wave per chunk, strided) + masked softmax, drop chunk 0
__global__ __launch_bounds__(256) void k_chunks(const float* __restrict__ hl,
                                                const int* __restrict__ hmask,
                                                const float* __restrict__ qc,
                                                float* __restrict__ out_ac) {
    __shared__ alignas(16) float q[D];
    __shared__ float sc[C];
    __shared__ float red[2];
    int b = blockIdx.x, t = threadIdx.x;
    for (int i = t; i < D / 4; i += 256)
        *(float4*)(&q[i * 4]) = *(const float4*)(qc + (size_t)b * D + i * 4);
    __syncthreads();
    int w = t >> 6, l = t & 63;
    for (int c = w; c < C; c += 4) {
        const float4* hp = (const float4*)(hl + (size_t)(c * B + b) * D);
        float acc = 0.f;
#pragma unroll
        for (int i = 0; i < 4; ++i) {
            int f = l + 64 * i;
            float4 h = hp[f];
            acc += dot4(h, &q[f * 4]);
        }
        for (int o = 32; o >= 1; o >>= 1) acc += __shfl_xor(acc, o);
        if (l == 0) sc[c] = acc;
    }
    __syncthreads();
    if (t == 0) {
        float mx = -1e30f;
        for (int c = 0; c < C; ++c) {
            float v = hmask[b * C + c] ? -1e30f : sc[c];
            mx = fmaxf(mx, v);
        }
        float sm = 0.f;
        for (int c = 0; c < C; ++c) {
            float v = hmask[b * C + c] ? -1e30f : sc[c];
            sm += __expf(v - mx);
        }
        red[0] = mx;
        red[1] = sm;
    }
    __syncthreads();
    if (t >= 1 && t < C) {
        bool m = hmask[b * C + t] != 0;
        float p = m ? 0.f : __expf(sc[t] - red[0]) / red[1];
        out_ac[b * NENT + (t - 1)] = p;
    }
}

// grid (8, B): (s-slab, batch). Block owns full D for one 256-row s-slab of one batch.
// No atomics: writes slab partials pf[ss][b][d]. Also writes out_av (once per s).
__global__ __launch_bounds__(256) void k_ctx(const float* __restrict__ ll,
                                             const float* __restrict__ out_au,
                                             const float* __restrict__ out_ac,
                                             float* __restrict__ pf,
                                             float* __restrict__ out_av) {
    __shared__ float s_av[256];
    int ss = blockIdx.x, b = blockIdx.y, t = threadIdx.x;
    {
        int s = ss * 256 + t;
        int n = s >> 5;  // ENT=32
        float a = out_ac[b * NENT + n] * out_au[b * S + s];
        s_av[t] = a;
        out_av[b * S + s] = a;
    }
    __syncthreads();
    float4 acc = {0.f, 0.f, 0.f, 0.f};
    const float4* base = (const float4*)(ll + (size_t)(ss * 256) * B * D + (size_t)b * D) + t;
#pragma unroll 8
    for (int j = 0; j < 256; ++j) {
        float4 x = base[(size_t)j * (B * D / 4)];
        float wv = s_av[j];
        acc.x += wv * x.x;
        acc.y += wv * x.y;
        acc.z += wv * x.z;
        acc.w += wv * x.w;
    }
    *(float4*)(pf + (size_t)ss * B * D + (size_t)b * D + t * 4) = acc;
}

// grid (B*D/256): cf = sum over 8 slab partials
__global__ __launch_bounds__(256) void k_red(const float* __restrict__ pf,
                                             float* __restrict__ cf) {
    int f = blockIdx.x * 256 + threadIdx.x;
    float s = 0.f;
#pragma unroll
    for (int ss = 0; ss < 8; ++ss) s += pf[(size_t)ss * B * D + f];
    cf[f] = s;
}

// grid (16, 8): x = 64-row group of W_out, y = 4-batch group.
// Linear id = x + 16*y -> all 8 same-Wo-slice blocks land on one XCD (L2 reuse).
__global__ __launch_bounds__(256) void k_out(const float* __restrict__ Wo,
                                             const float* __restrict__ src,
                                             const float* __restrict__ cf,
                                             float* __restrict__ out_h) {
    __shared__ alignas(16) float cc[4][2 * D];      // 32 KB concat for 4 batches
    __shared__ float red[4][64][4];                 // 4 KB
    int t = threadIdx.x, jg = blockIdx.x, bg = blockIdx.y;
    for (int f = t; f < 4 * (2 * D / 4); f += 256) {  // 2048 float4s
        int bb = f >> 9, part = f & 511;
        int b = bg * 4 + bb;
        float4 v;
        if (part < 256) v = *(const float4*)(cf + (size_t)b * D + part * 4);
        else v = *(const float4*)(src + (size_t)b * D + (part - 256) * 4);
        *(float4*)(&cc[bb][part * 4]) = v;
    }
    __syncthreads();
    int jl = t & 63, kq = t >> 6;
    int j = jg * 64 + jl;
    const float4* wp = (const float4*)(Wo + (size_t)j * 2 * D) + kq * 128;  // 512 k
    float acc[4] = {0.f, 0.f, 0.f, 0.f};
#pragma unroll 4
    for (int i = 0; i < 128; ++i) {
        float4 w = wp[i];
        int k = kq * 512 + i * 4;
#pragma unroll
        for (int bb = 0; bb < 4; ++bb) acc[bb] += dot4(w, &cc[bb][k]);
    }
#pragma unroll
    for (int bb = 0; bb < 4; ++bb) red[kq][jl][bb] = acc[bb];
    __syncthreads();
    {
        int jl2 = t & 63, bb = t >> 6;
        float s = red[0][jl2][bb] + red[1][jl2][bb] + red[2][jl2][bb] + red[3][jl2][bb];
        out_h[(size_t)(bg * 4 + bb) * D + jg * 64 + jl2] = tanhf(s);
    }
}

extern "C" void kernel_launch(void* const* d_in, const int* in_sizes, int n_in,
                              void* d_out, int out_size, void* d_ws, size_t ws_size,
                              hipStream_t stream) {
    const float* src = (const float*)d_in[0];
    const float* hl = (const float*)d_in[1];
    const float* pe = (const float*)d_in[2];
    const float* ll = (const float*)d_in[3];
    const int* lmask = (const int*)d_in[4];
    const int* hmask = (const int*)d_in[5];
    const float* Wu = (const float*)d_in[6];
    const float* Wc = (const float*)d_in[7];
    const float* Wo = (const float*)d_in[8];

    float* out = (float*)d_out;
    float* out_h = out;                      // (B, D)
    float* out_av = out + B * D;             // (B, S)
    float* out_ac = out_av + B * S;          // (B, NENT)
    float* out_au = out_ac + B * NENT;       // (B, S)

    float* ws = (float*)d_ws;
    float* qu = ws;                          // B*UD
    float* qc = qu + B * UD;                 // B*D
    float* cf = qc + B * D;                  // B*D
    float* pf = cf + B * D;                  // 8*B*D slab partials

    k_proj<<<dim3(20, 8), 256, 0, stream>>>(src, Wu, Wc, qu, qc);
    k_units<<<dim3(NENT, B), 256, 0, stream>>>(pe, lmask, qu, out_au);
    k_chunks<<<dim3(B), 256, 0, stream>>>(hl, hmask, qc, out_ac);
    k_ctx<<<dim3(8, B), 256, 0, stream>>>(ll, out_au, out_ac, pf, out_av);
    k_red<<<dim3(B * D / 256), 256, 0, stream>>>(pf, cf);
    k_out<<<dim3(16, 8), 256, 0, stream>>>(Wo, src, cf, out_h);
}